// Round 15
// baseline (1329.268 us; speedup 1.0000x reference)
//
#include <hip/hip_runtime.h>
#include <stdint.h>
#include <stddef.h>

typedef unsigned short u16;
typedef __attribute__((ext_vector_type(8))) short short8;
typedef __attribute__((ext_vector_type(4))) short short4v;
typedef __attribute__((ext_vector_type(4))) float f32x4;

#define DEV static __device__ __forceinline__

DEV float bf2f(u16 u){ return __uint_as_float(((unsigned)u)<<16); }
DEV u16 f2bf(float f){ unsigned x=__float_as_uint(f); return (u16)((x + 0x7fffu + ((x>>16)&1u))>>16); }

DEV float wsum(float v){
#pragma unroll
  for(int o=32;o;o>>=1) v += __shfl_xor(v,o);
  return v;
}
DEV float wmax(float v){
#pragma unroll
  for(int o=32;o;o>>=1) v = fmaxf(v,__shfl_xor(v,o));
  return v;
}
DEV float sigm(float x){ return __fdividef(1.f, 1.f+__expf(-x)); }
DEV float tanhx(float x){ float e=__expf(-2.f*fabsf(x)); float t=__fdividef(1.f-e,1.f+e); return x<0.f?-t:t; }

DEV f32x4 mfma16(short8 a, short8 b, f32x4 c){
  asm("v_mfma_f32_16x16x32_bf16 %0, %1, %2, %0" : "+v"(c) : "v"(a), "v"(b));
  return c;
}
DEV void gll16(const void* g, void* l){
  __builtin_amdgcn_global_load_lds((const __attribute__((address_space(1))) void*)g,
                                   (__attribute__((address_space(3))) void*)l, 16, 0, 0);
}

DEV void pack8(u16* dst, const float* src){
  const float4 a=*(const float4*)(src);
  const float4 b=*(const float4*)(src+4);
  short8 o;
  o[0]=(short)f2bf(a.x); o[1]=(short)f2bf(a.y); o[2]=(short)f2bf(a.z); o[3]=(short)f2bf(a.w);
  o[4]=(short)f2bf(b.x); o[5]=(short)f2bf(b.y); o[6]=(short)f2bf(b.z); o[7]=(short)f2bf(b.w);
  *(short8*)dst=o;
}
DEV void zero8(u16* dst){
  short8 z;
#pragma unroll
  for(int e=0;e<8;++e) z[e]=0;
  *(short8*)dst=z;
}

// ---------------------------------------------------------------------------
// setup: fp32->bf16 casts, weight reorders, embedding gather, combined bias.
// Gate rows unit-major: new row r <-> orig row o=((r&3)<<9)+(r>>2).
// ---------------------------------------------------------------------------
__global__ __launch_bounds__(256) void setup_cast(
  const float* __restrict__ feats, const int* __restrict__ captions,
  const float* __restrict__ embW, const float* __restrict__ Wf_w,
  const float* __restrict__ Wh_w, const float* __restrict__ W_ih,
  const float* __restrict__ W_hh, const float* __restrict__ b_ih,
  const float* __restrict__ b_hh, const float* __restrict__ out_w,
  u16* __restrict__ feats_bf, u16* __restrict__ outw_bf, u16* __restrict__ Wc,
  u16* __restrict__ WihE, u16* __restrict__ embx, u16* __restrict__ Whw_bf,
  u16* __restrict__ Wf_bf, float* __restrict__ bias_comb)
{
  const long long o0=12845056LL,o1=28246016LL,o2=30343168LL,o3=31391744LL,
                  o4=32702464LL,o5=32964608LL,o6=33226752LL,total=33228800LL;
  for (long long i8=((long long)blockIdx.x*256+threadIdx.x)*8; i8<total;
       i8+=(long long)gridDim.x*256*8){
    const long long i=i8;
    if (i<o0){ pack8(feats_bf+i, feats+i); }
    else if (i<o1){ const long long j=i-o0; const int r=(int)(j>>9);
      if (r<30000) pack8(outw_bf+j, out_w+j); else zero8(outw_bf+j); }
    else if (i<o2){ const long long j=i-o1; const int r=(int)(j>>10), k=(int)(j&1023);
      const int o=((r&3)<<9)+(r>>2);
      const float* s=(k<512)? (W_ih+(size_t)o*1024+512+k) : (W_hh+(size_t)o*512+(k-512));
      pack8(Wc+j, s); }
    else if (i<o3){ const long long j=i-o2; const int r=(int)(j>>9), k=(int)(j&511);
      const int o=((r&3)<<9)+(r>>2);
      pack8(WihE+j, W_ih+(size_t)o*1024+k); }
    else if (i<o4){ const long long j=i-o3; const int m=(int)(j>>9), e=(int)(j&511);
      const int b=m/20, tt=m-b*20; const int idx=captions[b*21+tt];
      if (idx) pack8(embx+j, embW+(size_t)idx*512+e); else zero8(embx+j); }
    else if (i<o5){ const long long j=i-o4; pack8(Whw_bf+j, Wh_w+j); }
    else if (i<o6){ const long long j=i-o5; pack8(Wf_bf+j, Wf_w+j); }
    else { const long long j=i-o6;
      for(int e=0;e<8;++e){ const int r=(int)(j+e); const int o=((r&3)<<9)+(r>>2);
        bias_comb[r]=b_ih[o]+b_hh[o]; } }
  }
}

// ---------------------------------------------------------------------------
// prep: gfeat = mean(feats), h0/c0. h0 (bf16) -> xs h-slot, c0 -> cbuf[0].
// ---------------------------------------------------------------------------
__global__ __launch_bounds__(256) void prep(
  const float* __restrict__ feats, const float* __restrict__ init_w,
  const float* __restrict__ init_b, const float* __restrict__ initc_w,
  const float* __restrict__ initc_b, u16* __restrict__ xs0, float* __restrict__ cbuf)
{
  const int b=blockIdx.x, tid=threadIdx.x, lane=tid&63, w=tid>>6;
  __shared__ float gf[512];
  const float* fb=feats+(size_t)b*196*512;
  float a0=0.f,a1=0.f;
  for(int n=0;n<196;++n){ a0+=fb[(size_t)n*512+tid]; a1+=fb[(size_t)n*512+tid+256]; }
  gf[tid]=a0*(1.f/196.f); gf[tid+256]=a1*(1.f/196.f);
  __syncthreads();
  const int kb=lane*8;
  float g8[8];
#pragma unroll
  for(int e=0;e<8;++e) g8[e]=gf[kb+e];
  for(int j=w*128;j<w*128+128;++j){
    const float* r1=init_w+(size_t)j*512+kb;
    const float* r2=initc_w+(size_t)j*512+kb;
    float s1=0.f,s2=0.f;
#pragma unroll
    for(int e=0;e<8;++e){ s1+=g8[e]*r1[e]; s2+=g8[e]*r2[e]; }
    s1=wsum(s1); s2=wsum(s2);
    if(lane==(j&63)){ xs0[b*1024+512+j]=f2bf(s1+init_b[j]); cbuf[b*512+j]=s2+initc_b[j]; }
  }
}

// ---------------------------------------------------------------------------
// attn_pair: 256 blocks x 1024 threads, siblings (b=blk>>1, h=blk&1).
// LSTM prologue + hproj REDUNDANT per sibling (bit-identical values; cbuf
// ping-pong so both read old buf / write new buf — r10-proven).
// Scores SPLIT: sibling h computes rows [98h, 98h+98) -> sc_g, then pairwise
// flag sync (r8-validated fence sequence, monotonic flags). Softmax redundant
// from sc_g; ctx SPLIT by columns (256 each) -> xs ctx half.
// ---------------------------------------------------------------------------
__global__ __launch_bounds__(1024) void attn_pair(
  const u16* __restrict__ fproj, const u16* __restrict__ feats_bf,
  u16* __restrict__ xs, const u16* __restrict__ Whw,
  const float* __restrict__ Whb, const float* __restrict__ vw,
  const float* __restrict__ vb, const float* __restrict__ gemb,
  const float* __restrict__ gpart, float* __restrict__ cbuf,
  u16* __restrict__ h_all, float* __restrict__ sc_g,
  unsigned* __restrict__ flags, int t)
{
  const int blk=blockIdx.x, tid=threadIdx.x, lane=tid&63, w=tid>>6;
  const int b=blk>>1, h=blk&1;
  __shared__ float part[16][256];
  __shared__ float hsf[512], hp[512], scw[208], red[16];
  if (t>0){
    if (tid<512){
      const int u=tid;
      float4 g4=*(const float4*)&gemb[((size_t)b*20+(t-1))*2048+u*4];
#pragma unroll
      for(int kz=0;kz<8;++kz){
        const float4 p=*(const float4*)&gpart[((size_t)kz*128+b)*2048+u*4];
        g4.x+=p.x; g4.y+=p.y; g4.z+=p.z; g4.w+=p.w;
      }
      const float cold=cbuf[((t-1)&1)*65536 + b*512+u];
      const float cn=sigm(g4.y)*cold+sigm(g4.x)*tanhx(g4.z);
      const float hn=sigm(g4.w)*tanhx(cn);
      cbuf[(t&1)*65536 + b*512+u]=cn;
      const u16 hb=f2bf(hn);
      xs[b*1024+512+u]=hb;
      h_all[((size_t)b*20+(t-1))*512+u]=hb;
      hsf[u]=bf2f(hb);
    }
  } else {
    if (tid<512) hsf[tid]=bf2f(xs[b*1024+512+tid]);
  }
  __syncthreads();
  const int kb=lane*8;
  float h8[8];
#pragma unroll
  for(int e=0;e<8;++e) h8[e]=hsf[kb+e];
  // hproj (redundant): wave w owns rows [32w, 32w+32), 8 rows per iteration
#pragma unroll
  for(int jj=0;jj<32;jj+=8){
    const int j=w*32+jj;
    short8 wv[8];
#pragma unroll
    for(int r=0;r<8;++r) wv[r]=*(const short8*)(Whw+(size_t)(j+r)*512+kb);
    float s[8];
#pragma unroll
    for(int r=0;r<8;++r) s[r]=0.f;
#pragma unroll
    for(int e=0;e<8;++e){
      const float he=h8[e];
#pragma unroll
      for(int r=0;r<8;++r) s[r]+=he*bf2f((u16)wv[r][e]);
    }
#pragma unroll
    for(int r=0;r<8;++r) s[r]=wsum(s[r]);
    if(lane==0){
#pragma unroll
      for(int r=0;r<8;++r) hp[j+r]=s[r]+Whb[j+r];
    }
  }
  __syncthreads();
  // scores (split): rows 98h + {w+16i, i=0..5} (96 rows) + leftover 98h+96+w
  float p2[8], vm2[8];
  float sv=0.f;
#pragma unroll
  for(int e=0;e<8;++e){
    const float p=hp[kb+e], v=vw[kb+e];
    p2[e]=2.f*p; vm2[e]=-2.f*v; sv+=v;
  }
  const float vb0=vb[0];
  {
    const int n0=98*h+w;
    short8 f[6];
#pragma unroll
    for(int r=0;r<6;++r) f[r]=*(const short8*)(fproj+((size_t)b*196+n0+16*r)*512+kb);
    float s[6];
#pragma unroll
    for(int r=0;r<6;++r) s[r]=sv;
#pragma unroll
    for(int e=0;e<8;++e){
#pragma unroll
      for(int r=0;r<6;++r)
        s[r]+=__fdividef(vm2[e],__expf(fmaf(bf2f((u16)f[r][e]),2.f,p2[e]))+1.f);
    }
#pragma unroll
    for(int r=0;r<6;++r) s[r]=wsum(s[r]);
    if(lane==0){
#pragma unroll
      for(int r=0;r<6;++r) sc_g[b*224+n0+16*r]=s[r]+vb0;
    }
  }
  if (w<2){
    const int n=98*h+96+w;
    short8 f0=*(const short8*)(fproj+((size_t)b*196+n)*512+kb);
    float s0=sv;
#pragma unroll
    for(int e=0;e<8;++e)
      s0+=__fdividef(vm2[e],__expf(fmaf(bf2f((u16)f0[e]),2.f,p2[e]))+1.f);
    s0=wsum(s0);
    if(lane==0) sc_g[b*224+n]=s0+vb0;
  }
  // pairwise sync (r8-validated sequence; monotonic flags, target t+1)
  __syncthreads();
  if (tid==0){
    __threadfence();
    __hip_atomic_store(&flags[blk],(unsigned)(t+1),__ATOMIC_RELEASE,__HIP_MEMORY_SCOPE_AGENT);
    while(__hip_atomic_load(&flags[blk^1],__ATOMIC_ACQUIRE,__HIP_MEMORY_SCOPE_AGENT)<(unsigned)(t+1))
      __builtin_amdgcn_s_sleep(1);
    __threadfence();
  }
  __syncthreads();
  // softmax over 196 (redundant, from sc_g)
  float xv=(tid<196)? sc_g[b*224+tid] : -3.0e38f;
  float mx=wmax(xv);
  if(lane==0) red[w]=mx;
  __syncthreads();
  float mm=red[0];
#pragma unroll
  for(int i=1;i<16;++i) mm=fmaxf(mm,red[i]);
  float pv=(tid<196)? __expf(xv-mm) : 0.f;
  float ps=wsum(pv);
  __syncthreads();
  if(lane==0) red[w]=ps;
  __syncthreads();
  float tot=red[0];
#pragma unroll
  for(int i=1;i<16;++i) tot+=red[i];
  if(tid<196) scw[tid]=__fdividef(pv,tot);
  __syncthreads();
  // ctx (split): cols [256h + lane*4, +4), rows w+16i (2-row batching)
  float4 acc; acc.x=0.f; acc.y=0.f; acc.z=0.f; acc.w=0.f;
  const int cb=h*256+lane*4;
#pragma unroll
  for(int i=0;i<12;i+=2){
    const int n0=w+16*i, n1=n0+16;
    short4v v0=*(const short4v*)(feats_bf+((size_t)b*196+n0)*512+cb);
    short4v v1=*(const short4v*)(feats_bf+((size_t)b*196+n1)*512+cb);
    const float w0=scw[n0], w1=scw[n1];
    acc.x+=w0*bf2f((u16)v0[0])+w1*bf2f((u16)v1[0]);
    acc.y+=w0*bf2f((u16)v0[1])+w1*bf2f((u16)v1[1]);
    acc.z+=w0*bf2f((u16)v0[2])+w1*bf2f((u16)v1[2]);
    acc.w+=w0*bf2f((u16)v0[3])+w1*bf2f((u16)v1[3]);
  }
  {
    const int n=w+192;
    if (n<196){
      short4v v0=*(const short4v*)(feats_bf+((size_t)b*196+n)*512+cb);
      const float w0=scw[n];
      acc.x+=w0*bf2f((u16)v0[0]);
      acc.y+=w0*bf2f((u16)v0[1]);
      acc.z+=w0*bf2f((u16)v0[2]);
      acc.w+=w0*bf2f((u16)v0[3]);
    }
  }
  *(float4*)&part[w][lane*4]=acc;
  __syncthreads();
  if (tid<256){
    float s=0.f;
#pragma unroll
    for(int i=0;i<16;++i) s+=part[i][tid];
    xs[b*1024 + h*256 + tid]=f2bf(s);
  }
}

// ---------------------------------------------------------------------------
// lstm_fin: LSTM for the final step (t=19) — h_all only. Reads cbuf[1] (c18).
// ---------------------------------------------------------------------------
__global__ __launch_bounds__(512) void lstm_fin(
  const float* __restrict__ gemb, const float* __restrict__ gpart,
  const float* __restrict__ cbuf, u16* __restrict__ h_all)
{
  const int b=blockIdx.x, u=threadIdx.x;
  float4 g4=*(const float4*)&gemb[((size_t)b*20+19)*2048+u*4];
#pragma unroll
  for(int kz=0;kz<8;++kz){
    const float4 p=*(const float4*)&gpart[((size_t)kz*128+b)*2048+u*4];
    g4.x+=p.x; g4.y+=p.y; g4.z+=p.z; g4.w+=p.w;
  }
  const float cn=sigm(g4.y)*cbuf[65536 + b*512+u]+sigm(g4.x)*tanhx(g4.z);
  const float hn=sigm(g4.w)*tanhx(cn);
  h_all[((size_t)b*20+19)*512+u]=f2bf(hn);
}

// ---------------------------------------------------------------------------
// gemm_bt: C[M,N] = A[M,K] * B[N,K]^T, 128x128 tile, m97 structure.
// MODE 0: bf16 out + bias   MODE 1: f32 out + bias
// MODE 2: f32 + col guard, transposed grid (out_w L2 reuse)
// MODE 4: K-split partial (blockIdx.y = kz, base += kz*K, bm=0), 8 x K=128
// ---------------------------------------------------------------------------
template<int MODE>
__global__ __launch_bounds__(256) void gemm_bt(
  const u16* __restrict__ A, int lda, const u16* __restrict__ Bw, int ldb, int K,
  const float* __restrict__ bias, float* __restrict__ outf, u16* __restrict__ outb,
  int ncols)
{
  const int bm=(MODE==4)? 0 : ((MODE==2)? blockIdx.x*128 : blockIdx.y*128);
  const int bn=(MODE==2)? blockIdx.y*128 : blockIdx.x*128;
  const int kz=(MODE==4)? blockIdx.y : 0;
  const u16* __restrict__ Ap=A +(size_t)kz*K;
  const u16* __restrict__ Bp=Bw+(size_t)kz*K;
  const int tid=threadIdx.x, lane=tid&63, wave=tid>>6;
  const int wr=(wave>>1)*64, wc=(wave&1)*64;
  __shared__ u16 As[128*32], Bs[128*32];
  f32x4 acc[4][4]={};
  const int srow=tid>>2, scol=(tid&3)*8;
  for(int k0=0;k0<K;k0+=32){
    gll16(Ap+(size_t)(bm+srow)*lda    +k0+scol, As+tid*8);
    gll16(Ap+(size_t)(bm+64+srow)*lda +k0+scol, As+2048+tid*8);
    gll16(Bp+(size_t)(bn+srow)*ldb    +k0+scol, Bs+tid*8);
    gll16(Bp+(size_t)(bn+64+srow)*ldb +k0+scol, Bs+2048+tid*8);
    __syncthreads();
    short8 af[4], bfr[4];
    const int ro=lane&15, ko=(lane>>4)*8;
#pragma unroll
    for(int m=0;m<4;++m) af[m]=*(const short8*)(As+(wr+m*16+ro)*32+ko);
#pragma unroll
    for(int n=0;n<4;++n) bfr[n]=*(const short8*)(Bs+(wc+n*16+ro)*32+ko);
#pragma unroll
    for(int m=0;m<4;++m)
#pragma unroll
      for(int n=0;n<4;++n) acc[m][n]=mfma16(af[m],bfr[n],acc[m][n]);
    __syncthreads();
  }
  asm volatile("s_nop 7\ns_nop 7\ns_nop 7");  // MFMA->VALU hazard guard
  const int ro4=(lane>>4)*4, co=lane&15;
#pragma unroll
  for(int m=0;m<4;++m)
#pragma unroll
    for(int n=0;n<4;++n)
#pragma unroll
      for(int j=0;j<4;++j){
        const int r=bm+wr+m*16+ro4+j, c=bn+wc+n*16+co;
        if constexpr (MODE==0)      outb[(size_t)r*ncols+c]=f2bf(acc[m][n][j]+bias[c]);
        else if constexpr (MODE==1) outf[(size_t)r*ncols+c]=acc[m][n][j]+bias[c];
        else if constexpr (MODE==2){ if (c<ncols) outf[(size_t)r*ncols+c]=acc[m][n][j]+bias[c]; }
        else                        outf[((size_t)kz*128+r)*ncols+c]=acc[m][n][j];
      }
}

// ---------------------------------------------------------------------------
extern "C" void kernel_launch(void* const* d_in, const int* in_sizes, int n_in,
                              void* d_out, int out_size, void* d_ws, size_t ws_size,
                              hipStream_t stream) {
  const float* feats   =(const float*)d_in[0];
  const int*   captions=(const int*)  d_in[1];
  const float* embW    =(const float*)d_in[2];
  const float* Wf_w    =(const float*)d_in[3];
  const float* Wf_b    =(const float*)d_in[4];
  const float* Wh_w    =(const float*)d_in[5];
  const float* Wh_b    =(const float*)d_in[6];
  const float* v_w     =(const float*)d_in[7];
  const float* v_b     =(const float*)d_in[8];
  const float* W_ih    =(const float*)d_in[9];
  const float* W_hh    =(const float*)d_in[10];
  const float* b_ih    =(const float*)d_in[11];
  const float* b_hh    =(const float*)d_in[12];
  const float* init_w  =(const float*)d_in[13];
  const float* init_b  =(const float*)d_in[14];
  const float* initc_w =(const float*)d_in[15];
  const float* initc_b =(const float*)d_in[16];
  const float* out_w   =(const float*)d_in[17];
  const float* out_b   =(const float*)d_in[18];
  float* out=(float*)d_out;
  char* ws=(char*)d_ws;

  u16*   feats_bf =(u16*)  (ws+0);
  u16*   fproj    =(u16*)  (ws+25690112);
  u16*   outw_bf  =(u16*)  (ws+51380224);
  u16*   Wc       =(u16*)  (ws+82182144);
  u16*   WihE     =(u16*)  (ws+86376448);
  u16*   Whw_bf   =(u16*)  (ws+88473600);
  u16*   Wf_bf    =(u16*)  (ws+88997888);
  u16*   embx     =(u16*)  (ws+89522176);
  u16*   h_all    =(u16*)  (ws+92143616);
  u16*   xs0      =(u16*)  (ws+94765056);
  float* gemb     =(float*)(ws+95289344);
  float* cbuf     =(float*)(ws+116260864);  // 2 x 128 x 512 f32 (ping-pong)
  float* bias_comb=(float*)(ws+116785152);
  float* gpart    =(float*)(ws+116793344);  // 8 x 128 x 2048 f32 = 8 MB
  float* sc_g     =(float*)(ws+125200000);  // 128 x 224 f32
  unsigned* flags =(unsigned*)(ws+125400064); // 256 u32

  hipMemsetAsync(flags, 0, 1024, stream);
  setup_cast<<<4096,256,0,stream>>>(feats,captions,embW,Wf_w,Wh_w,W_ih,W_hh,b_ih,b_hh,out_w,
                                    feats_bf,outw_bf,Wc,WihE,embx,Whw_bf,Wf_bf,bias_comb);
  prep<<<128,256,0,stream>>>(feats,init_w,init_b,initc_w,initc_b,xs0,cbuf);
  // fproj = feats_bf @ Wf^T + Wf_b  (25088 x 512, K=512) -> bf16
  gemm_bt<0><<<dim3(4,196),256,0,stream>>>(feats_bf,512,Wf_bf,512,512,
      Wf_b,nullptr,fproj,512);
  // gemb = embx @ WihE^T + (b_ih+b_hh)  (2560 x 2048, K=512) -> f32
  gemm_bt<1><<<dim3(16,20),256,0,stream>>>(embx,512,WihE,512,512,
      bias_comb,gemb,nullptr,2048);

  for(int t=0;t<20;++t){
    attn_pair<<<256,1024,0,stream>>>(fproj,feats_bf,xs0,Whw_bf,Wh_b,v_w,v_b,
                                     gemb,gpart,cbuf,h_all,sc_g,flags,t);
    // gates partials: xs(128x1024) @ Wc^T(2048x1024), K-split 8x128 -> gpart
    gemm_bt<4><<<dim3(16,8),256,0,stream>>>(xs0,1024,Wc,1024,128,
        nullptr,gpart,nullptr,2048);
  }
  lstm_fin<<<128,512,0,stream>>>(gemb,gpart,cbuf,h_all);
  // logits = h_all @ out_w^T + out_b, transposed grid for out_w L2 reuse
  gemm_bt<2><<<dim3(20,235),256,0,stream>>>(h_all,512,outw_bf,512,512,
      out_b,out,nullptr,30000);
}

// Round 16
// 1124.501 us; speedup vs baseline: 1.1821x; 1.1821x over previous
//
#include <hip/hip_runtime.h>
#include <stdint.h>
#include <stddef.h>

typedef unsigned short u16;
typedef __attribute__((ext_vector_type(8))) short short8;
typedef __attribute__((ext_vector_type(4))) float f32x4;

#define DEV static __device__ __forceinline__

DEV float bf2f(u16 u){ return __uint_as_float(((unsigned)u)<<16); }
DEV u16 f2bf(float f){ unsigned x=__float_as_uint(f); return (u16)((x + 0x7fffu + ((x>>16)&1u))>>16); }

DEV float wsum(float v){
#pragma unroll
  for(int o=32;o;o>>=1) v += __shfl_xor(v,o);
  return v;
}
DEV float sigm(float x){ return __fdividef(1.f, 1.f+__expf(-x)); }
DEV float tanhx(float x){ float e=__expf(-2.f*fabsf(x)); float t=__fdividef(1.f-e,1.f+e); return x<0.f?-t:t; }

DEV f32x4 mfma16(short8 a, short8 b, f32x4 c){
  asm("v_mfma_f32_16x16x32_bf16 %0, %1, %2, %0" : "+v"(c) : "v"(a), "v"(b));
  return c;
}
DEV void gll16(const void* g, void* l){
  __builtin_amdgcn_global_load_lds((const __attribute__((address_space(1))) void*)g,
                                   (__attribute__((address_space(3))) void*)l, 16, 0, 0);
}

DEV void pack8(u16* dst, const float* src){
  const float4 a=*(const float4*)(src);
  const float4 b=*(const float4*)(src+4);
  short8 o;
  o[0]=(short)f2bf(a.x); o[1]=(short)f2bf(a.y); o[2]=(short)f2bf(a.z); o[3]=(short)f2bf(a.w);
  o[4]=(short)f2bf(b.x); o[5]=(short)f2bf(b.y); o[6]=(short)f2bf(b.z); o[7]=(short)f2bf(b.w);
  *(short8*)dst=o;
}
DEV void zero8(u16* dst){
  short8 z;
#pragma unroll
  for(int e=0;e<8;++e) z[e]=0;
  *(short8*)dst=z;
}

// ---------------------------------------------------------------------------
// setup: fp32->bf16 casts, weight reorders, embedding gather, combined bias.
// Gate rows unit-major: new row r <-> orig row o=((r&3)<<9)+(r>>2).
// ---------------------------------------------------------------------------
__global__ __launch_bounds__(256) void setup_cast(
  const float* __restrict__ feats, const int* __restrict__ captions,
  const float* __restrict__ embW, const float* __restrict__ Wf_w,
  const float* __restrict__ Wh_w, const float* __restrict__ W_ih,
  const float* __restrict__ W_hh, const float* __restrict__ b_ih,
  const float* __restrict__ b_hh, const float* __restrict__ out_w,
  u16* __restrict__ feats_bf, u16* __restrict__ outw_bf, u16* __restrict__ Wc,
  u16* __restrict__ WihE, u16* __restrict__ embx, u16* __restrict__ Whw_bf,
  u16* __restrict__ Wf_bf, float* __restrict__ bias_comb)
{
  const long long o0=12845056LL,o1=28246016LL,o2=30343168LL,o3=31391744LL,
                  o4=32702464LL,o5=32964608LL,o6=33226752LL,total=33228800LL;
  for (long long i8=((long long)blockIdx.x*256+threadIdx.x)*8; i8<total;
       i8+=(long long)gridDim.x*256*8){
    const long long i=i8;
    if (i<o0){ pack8(feats_bf+i, feats+i); }
    else if (i<o1){ const long long j=i-o0; const int r=(int)(j>>9);
      if (r<30000) pack8(outw_bf+j, out_w+j); else zero8(outw_bf+j); }
    else if (i<o2){ const long long j=i-o1; const int r=(int)(j>>10), k=(int)(j&1023);
      const int o=((r&3)<<9)+(r>>2);
      const float* s=(k<512)? (W_ih+(size_t)o*1024+512+k) : (W_hh+(size_t)o*512+(k-512));
      pack8(Wc+j, s); }
    else if (i<o3){ const long long j=i-o2; const int r=(int)(j>>9), k=(int)(j&511);
      const int o=((r&3)<<9)+(r>>2);
      pack8(WihE+j, W_ih+(size_t)o*1024+k); }
    else if (i<o4){ const long long j=i-o3; const int m=(int)(j>>9), e=(int)(j&511);
      const int b=m/20, tt=m-b*20; const int idx=captions[b*21+tt];
      if (idx) pack8(embx+j, embW+(size_t)idx*512+e); else zero8(embx+j); }
    else if (i<o5){ const long long j=i-o4; pack8(Whw_bf+j, Wh_w+j); }
    else if (i<o6){ const long long j=i-o5; pack8(Wf_bf+j, Wf_w+j); }
    else { const long long j=i-o6;
      for(int e=0;e<8;++e){ const int r=(int)(j+e); const int o=((r&3)<<9)+(r>>2);
        bias_comb[r]=b_ih[o]+b_hh[o]; } }
  }
}

// ---------------------------------------------------------------------------
// prep: gfeat = mean(feats), h0/c0. h0 (bf16) -> xs h-slot, c0 (fp32) -> cbuf.
// ---------------------------------------------------------------------------
__global__ __launch_bounds__(256) void prep(
  const float* __restrict__ feats, const float* __restrict__ init_w,
  const float* __restrict__ init_b, const float* __restrict__ initc_w,
  const float* __restrict__ initc_b, u16* __restrict__ xs0, float* __restrict__ cbuf)
{
  const int b=blockIdx.x, tid=threadIdx.x, lane=tid&63, w=tid>>6;
  __shared__ float gf[512];
  const float* fb=feats+(size_t)b*196*512;
  float a0=0.f,a1=0.f;
  for(int n=0;n<196;++n){ a0+=fb[(size_t)n*512+tid]; a1+=fb[(size_t)n*512+tid+256]; }
  gf[tid]=a0*(1.f/196.f); gf[tid+256]=a1*(1.f/196.f);
  __syncthreads();
  const int kb=lane*8;
  float g8[8];
#pragma unroll
  for(int e=0;e<8;++e) g8[e]=gf[kb+e];
  for(int j=w*128;j<w*128+128;++j){
    const float* r1=init_w+(size_t)j*512+kb;
    const float* r2=initc_w+(size_t)j*512+kb;
    float s1=0.f,s2=0.f;
#pragma unroll
    for(int e=0;e<8;++e){ s1+=g8[e]*r1[e]; s2+=g8[e]*r2[e]; }
    s1=wsum(s1); s2=wsum(s2);
    if(lane==(j&63)){ xs0[b*1024+512+j]=f2bf(s1+init_b[j]); cbuf[b*512+j]=s2+initc_b[j]; }
  }
}

// ---------------------------------------------------------------------------
// attn_step: 128 blocks x 1024 threads (16 waves). r14 structure with slimmed
// softmax: NO max-subtraction (scores bounded |s|<~8, exp safe in fp32;
// softmax(x-m)==softmax(x)), NO vb0 add (cancels in softmax), normalization
// deferred to ctx part-write (acc * 1/tot). Barriers 8 -> 5.
// Prologue (t>0): LSTM for step t-1 (8 gpart K-slices).
// ---------------------------------------------------------------------------
__global__ __launch_bounds__(1024) void attn_step(
  const u16* __restrict__ fproj, const u16* __restrict__ feats_bf,
  u16* __restrict__ xs, const u16* __restrict__ Whw,
  const float* __restrict__ Whb, const float* __restrict__ vw,
  const float* __restrict__ gemb,
  const float* __restrict__ gpart, float* __restrict__ cbuf,
  u16* __restrict__ h_all, int t)
{
  const int b=blockIdx.x, tid=threadIdx.x, lane=tid&63, w=tid>>6;
  __shared__ float part[16][512];
  __shared__ float hsf[512], hp[512], sc[208], red[16];
  if (t>0){
    if (tid<512){
      const int u=tid;
      float4 g4=*(const float4*)&gemb[((size_t)b*20+(t-1))*2048+u*4];
#pragma unroll
      for(int kz=0;kz<8;++kz){
        const float4 p=*(const float4*)&gpart[((size_t)kz*128+b)*2048+u*4];
        g4.x+=p.x; g4.y+=p.y; g4.z+=p.z; g4.w+=p.w;
      }
      const float cn=sigm(g4.y)*cbuf[b*512+u]+sigm(g4.x)*tanhx(g4.z);
      const float hn=sigm(g4.w)*tanhx(cn);
      cbuf[b*512+u]=cn;
      const u16 hb=f2bf(hn);
      xs[b*1024+512+u]=hb;
      h_all[((size_t)b*20+(t-1))*512+u]=hb;
      hsf[u]=bf2f(hb);
    }
  } else {
    if (tid<512) hsf[tid]=bf2f(xs[b*1024+512+tid]);
  }
  __syncthreads();
  const int kb=lane*8;
  float h8[8];
#pragma unroll
  for(int e=0;e<8;++e) h8[e]=hsf[kb+e];
  // hproj: wave w owns rows [32w, 32w+32), 8 rows per iteration
#pragma unroll
  for(int jj=0;jj<32;jj+=8){
    const int j=w*32+jj;
    short8 wv[8];
#pragma unroll
    for(int r=0;r<8;++r) wv[r]=*(const short8*)(Whw+(size_t)(j+r)*512+kb);
    float s[8];
#pragma unroll
    for(int r=0;r<8;++r) s[r]=0.f;
#pragma unroll
    for(int e=0;e<8;++e){
      const float he=h8[e];
#pragma unroll
      for(int r=0;r<8;++r) s[r]+=he*bf2f((u16)wv[r][e]);
    }
#pragma unroll
    for(int r=0;r<8;++r) s[r]=wsum(s[r]);
    if(lane==0){
#pragma unroll
      for(int r=0;r<8;++r) hp[j+r]=s[r]+Whb[j+r];
    }
  }
  __syncthreads();
  // scores: v·tanh(f+p) = v - 2v/(exp(2(f+p))+1); 6-row batching. Raw scores
  // (no vb0 — it cancels in softmax).
  float p2[8], vm2[8];
  float sv=0.f;
#pragma unroll
  for(int e=0;e<8;++e){
    const float p=hp[kb+e], v=vw[kb+e];
    p2[e]=2.f*p; vm2[e]=-2.f*v; sv+=v;
  }
#pragma unroll
  for(int i=0;i<12;i+=6){
    const int n0=w+16*i;
    short8 f[6];
#pragma unroll
    for(int r=0;r<6;++r) f[r]=*(const short8*)(fproj+((size_t)b*196+n0+16*r)*512+kb);
    float s[6];
#pragma unroll
    for(int r=0;r<6;++r) s[r]=sv;
#pragma unroll
    for(int e=0;e<8;++e){
#pragma unroll
      for(int r=0;r<6;++r)
        s[r]+=__fdividef(vm2[e],__expf(fmaf(bf2f((u16)f[r][e]),2.f,p2[e]))+1.f);
    }
#pragma unroll
    for(int r=0;r<6;++r) s[r]=wsum(s[r]);
    if(lane==0){
#pragma unroll
      for(int r=0;r<6;++r) sc[n0+16*r]=s[r];
    }
  }
  {
    const int n=w+192;
    if (n<196){
      short8 f0=*(const short8*)(fproj+((size_t)b*196+n)*512+kb);
      float s0=sv;
#pragma unroll
      for(int e=0;e<8;++e)
        s0+=__fdividef(vm2[e],__expf(fmaf(bf2f((u16)f0[e]),2.f,p2[e]))+1.f);
      s0=wsum(s0);
      if(lane==0) sc[n]=s0;
    }
  }
  __syncthreads();
  // softmax (no-max variant): pv=exp(s); tot=sum; weights stay raw in sc,
  // normalization deferred to ctx part-write.
  float pv=(tid<196)? __expf(sc[tid]) : 0.f;
  float ps=wsum(pv);
  if(lane==0) red[w]=ps;
  if(tid<196) sc[tid]=pv;
  __syncthreads();
  float tot=red[0];
#pragma unroll
  for(int i=1;i<16;++i) tot+=red[i];
  const float inv=__fdividef(1.f,tot);
  // ctx partials: wave w accumulates rows w+16i, 6-row batching
  float a8[8];
#pragma unroll
  for(int e=0;e<8;++e) a8[e]=0.f;
#pragma unroll
  for(int i=0;i<12;i+=6){
    const int n0=w+16*i;
    short8 v[6];
#pragma unroll
    for(int r=0;r<6;++r) v[r]=*(const short8*)(feats_bf+((size_t)b*196+n0+16*r)*512+kb);
    float wn[6];
#pragma unroll
    for(int r=0;r<6;++r) wn[r]=sc[n0+16*r];
#pragma unroll
    for(int e=0;e<8;++e){
      float acc=a8[e];
#pragma unroll
      for(int r=0;r<6;++r) acc+=wn[r]*bf2f((u16)v[r][e]);
      a8[e]=acc;
    }
  }
  {
    const int n=w+192;
    if (n<196){
      short8 v0=*(const short8*)(feats_bf+((size_t)b*196+n)*512+kb);
      const float wn=sc[n];
#pragma unroll
      for(int e=0;e<8;++e) a8[e]+=wn*bf2f((u16)v0[e]);
    }
  }
#pragma unroll
  for(int e=0;e<8;++e) a8[e]*=inv;
  *(float4*)&part[w][kb]  =*(float4*)&a8[0];
  *(float4*)&part[w][kb+4]=*(float4*)&a8[4];
  __syncthreads();
  if (tid<512){
    float s=0.f;
#pragma unroll
    for(int i=0;i<16;++i) s+=part[i][tid];
    xs[b*1024+tid]=f2bf(s);
  }
}

// ---------------------------------------------------------------------------
// lstm_fin: LSTM for the final step (t=19) — h_all only. 8 gpart slices.
// ---------------------------------------------------------------------------
__global__ __launch_bounds__(512) void lstm_fin(
  const float* __restrict__ gemb, const float* __restrict__ gpart,
  const float* __restrict__ cbuf, u16* __restrict__ h_all)
{
  const int b=blockIdx.x, u=threadIdx.x;
  float4 g4=*(const float4*)&gemb[((size_t)b*20+19)*2048+u*4];
#pragma unroll
  for(int kz=0;kz<8;++kz){
    const float4 p=*(const float4*)&gpart[((size_t)kz*128+b)*2048+u*4];
    g4.x+=p.x; g4.y+=p.y; g4.z+=p.z; g4.w+=p.w;
  }
  const float cn=sigm(g4.y)*cbuf[b*512+u]+sigm(g4.x)*tanhx(g4.z);
  const float hn=sigm(g4.w)*tanhx(cn);
  h_all[((size_t)b*20+19)*512+u]=f2bf(hn);
}

// ---------------------------------------------------------------------------
// gemm_bt: C[M,N] = A[M,K] * B[N,K]^T, 128x128 tile, m97 structure.
// MODE 0: bf16 out + bias   MODE 1: f32 out + bias
// MODE 2: f32 + col guard, transposed grid (out_w L2 reuse)
// MODE 4: K-split partial (blockIdx.y = kz, base += kz*K, bm=0), 8 x K=128
// ---------------------------------------------------------------------------
template<int MODE>
__global__ __launch_bounds__(256) void gemm_bt(
  const u16* __restrict__ A, int lda, const u16* __restrict__ Bw, int ldb, int K,
  const float* __restrict__ bias, float* __restrict__ outf, u16* __restrict__ outb,
  int ncols)
{
  const int bm=(MODE==4)? 0 : ((MODE==2)? blockIdx.x*128 : blockIdx.y*128);
  const int bn=(MODE==2)? blockIdx.y*128 : blockIdx.x*128;
  const int kz=(MODE==4)? blockIdx.y : 0;
  const u16* __restrict__ Ap=A +(size_t)kz*K;
  const u16* __restrict__ Bp=Bw+(size_t)kz*K;
  const int tid=threadIdx.x, lane=tid&63, wave=tid>>6;
  const int wr=(wave>>1)*64, wc=(wave&1)*64;
  __shared__ u16 As[128*32], Bs[128*32];
  f32x4 acc[4][4]={};
  const int srow=tid>>2, scol=(tid&3)*8;
  for(int k0=0;k0<K;k0+=32){
    gll16(Ap+(size_t)(bm+srow)*lda    +k0+scol, As+tid*8);
    gll16(Ap+(size_t)(bm+64+srow)*lda +k0+scol, As+2048+tid*8);
    gll16(Bp+(size_t)(bn+srow)*ldb    +k0+scol, Bs+tid*8);
    gll16(Bp+(size_t)(bn+64+srow)*ldb +k0+scol, Bs+2048+tid*8);
    __syncthreads();
    short8 af[4], bfr[4];
    const int ro=lane&15, ko=(lane>>4)*8;
#pragma unroll
    for(int m=0;m<4;++m) af[m]=*(const short8*)(As+(wr+m*16+ro)*32+ko);
#pragma unroll
    for(int n=0;n<4;++n) bfr[n]=*(const short8*)(Bs+(wc+n*16+ro)*32+ko);
#pragma unroll
    for(int m=0;m<4;++m)
#pragma unroll
      for(int n=0;n<4;++n) acc[m][n]=mfma16(af[m],bfr[n],acc[m][n]);
    __syncthreads();
  }
  asm volatile("s_nop 7\ns_nop 7\ns_nop 7");  // MFMA->VALU hazard guard
  const int ro4=(lane>>4)*4, co=lane&15;
#pragma unroll
  for(int m=0;m<4;++m)
#pragma unroll
    for(int n=0;n<4;++n)
#pragma unroll
      for(int j=0;j<4;++j){
        const int r=bm+wr+m*16+ro4+j, c=bn+wc+n*16+co;
        if constexpr (MODE==0)      outb[(size_t)r*ncols+c]=f2bf(acc[m][n][j]+bias[c]);
        else if constexpr (MODE==1) outf[(size_t)r*ncols+c]=acc[m][n][j]+bias[c];
        else if constexpr (MODE==2){ if (c<ncols) outf[(size_t)r*ncols+c]=acc[m][n][j]+bias[c]; }
        else                        outf[((size_t)kz*128+r)*ncols+c]=acc[m][n][j];
      }
}

// ---------------------------------------------------------------------------
extern "C" void kernel_launch(void* const* d_in, const int* in_sizes, int n_in,
                              void* d_out, int out_size, void* d_ws, size_t ws_size,
                              hipStream_t stream) {
  const float* feats   =(const float*)d_in[0];
  const int*   captions=(const int*)  d_in[1];
  const float* embW    =(const float*)d_in[2];
  const float* Wf_w    =(const float*)d_in[3];
  const float* Wf_b    =(const float*)d_in[4];
  const float* Wh_w    =(const float*)d_in[5];
  const float* Wh_b    =(const float*)d_in[6];
  const float* v_w     =(const float*)d_in[7];
  const float* v_b     =(const float*)d_in[8];
  const float* W_ih    =(const float*)d_in[9];
  const float* W_hh    =(const float*)d_in[10];
  const float* b_ih    =(const float*)d_in[11];
  const float* b_hh    =(const float*)d_in[12];
  const float* init_w  =(const float*)d_in[13];
  const float* init_b  =(const float*)d_in[14];
  const float* initc_w =(const float*)d_in[15];
  const float* initc_b =(const float*)d_in[16];
  const float* out_w   =(const float*)d_in[17];
  const float* out_b   =(const float*)d_in[18];
  float* out=(float*)d_out;
  char* ws=(char*)d_ws;
  (void)v_b;

  u16*   feats_bf =(u16*)  (ws+0);
  u16*   fproj    =(u16*)  (ws+25690112);
  u16*   outw_bf  =(u16*)  (ws+51380224);
  u16*   Wc       =(u16*)  (ws+82182144);
  u16*   WihE     =(u16*)  (ws+86376448);
  u16*   Whw_bf   =(u16*)  (ws+88473600);
  u16*   Wf_bf    =(u16*)  (ws+88997888);
  u16*   embx     =(u16*)  (ws+89522176);
  u16*   h_all    =(u16*)  (ws+92143616);
  u16*   xs0      =(u16*)  (ws+94765056);
  float* gemb     =(float*)(ws+95289344);
  float* cbuf     =(float*)(ws+116260864);
  float* bias_comb=(float*)(ws+116785152);
  float* gpart    =(float*)(ws+116793344);  // 8 x 128 x 2048 f32 = 8 MB

  setup_cast<<<4096,256,0,stream>>>(feats,captions,embW,Wf_w,Wh_w,W_ih,W_hh,b_ih,b_hh,out_w,
                                    feats_bf,outw_bf,Wc,WihE,embx,Whw_bf,Wf_bf,bias_comb);
  prep<<<128,256,0,stream>>>(feats,init_w,init_b,initc_w,initc_b,xs0,cbuf);
  // fproj = feats_bf @ Wf^T + Wf_b  (25088 x 512, K=512) -> bf16
  gemm_bt<0><<<dim3(4,196),256,0,stream>>>(feats_bf,512,Wf_bf,512,512,
      Wf_b,nullptr,fproj,512);
  // gemb = embx @ WihE^T + (b_ih+b_hh)  (2560 x 2048, K=512) -> f32
  gemm_bt<1><<<dim3(16,20),256,0,stream>>>(embx,512,WihE,512,512,
      bias_comb,gemb,nullptr,2048);

  for(int t=0;t<20;++t){
    attn_step<<<128,1024,0,stream>>>(fproj,feats_bf,xs0,Whw_bf,Wh_b,v_w,
                                     gemb,gpart,cbuf,h_all,t);
    // gates partials: xs(128x1024) @ Wc^T(2048x1024), K-split 8x128 -> gpart
    gemm_bt<4><<<dim3(16,8),256,0,stream>>>(xs0,1024,Wc,1024,128,
        nullptr,gpart,nullptr,2048);
  }
  lstm_fin<<<128,512,0,stream>>>(gemb,gpart,cbuf,h_all);
  // logits = h_all @ out_w^T + out_b, transposed grid for out_w L2 reuse
  gemm_bt<2><<<dim3(20,235),256,0,stream>>>(h_all,512,outw_bf,512,512,
      out_b,out,nullptr,30000);
}

// Round 17
// 1104.957 us; speedup vs baseline: 1.2030x; 1.0177x over previous
//
#include <hip/hip_runtime.h>
#include <stdint.h>
#include <stddef.h>

typedef unsigned short u16;
typedef __attribute__((ext_vector_type(8))) short short8;
typedef __attribute__((ext_vector_type(4))) float f32x4;

#define DEV static __device__ __forceinline__

DEV float bf2f(u16 u){ return __uint_as_float(((unsigned)u)<<16); }
DEV u16 f2bf(float f){ unsigned x=__float_as_uint(f); return (u16)((x + 0x7fffu + ((x>>16)&1u))>>16); }

DEV float wsum(float v){
#pragma unroll
  for(int o=32;o;o>>=1) v += __shfl_xor(v,o);
  return v;
}
DEV float sigm(float x){ return __fdividef(1.f, 1.f+__expf(-x)); }
DEV float tanhx(float x){ float e=__expf(-2.f*fabsf(x)); float t=__fdividef(1.f-e,1.f+e); return x<0.f?-t:t; }

DEV f32x4 mfma16(short8 a, short8 b, f32x4 c){
  asm("v_mfma_f32_16x16x32_bf16 %0, %1, %2, %0" : "+v"(c) : "v"(a), "v"(b));
  return c;
}
DEV void gll16(const void* g, void* l){
  __builtin_amdgcn_global_load_lds((const __attribute__((address_space(1))) void*)g,
                                   (__attribute__((address_space(3))) void*)l, 16, 0, 0);
}

DEV void pack8(u16* dst, const float* src){
  const float4 a=*(const float4*)(src);
  const float4 b=*(const float4*)(src+4);
  short8 o;
  o[0]=(short)f2bf(a.x); o[1]=(short)f2bf(a.y); o[2]=(short)f2bf(a.z); o[3]=(short)f2bf(a.w);
  o[4]=(short)f2bf(b.x); o[5]=(short)f2bf(b.y); o[6]=(short)f2bf(b.z); o[7]=(short)f2bf(b.w);
  *(short8*)dst=o;
}
DEV void zero8(u16* dst){
  short8 z;
#pragma unroll
  for(int e=0;e<8;++e) z[e]=0;
  *(short8*)dst=z;
}

// ---------------------------------------------------------------------------
// setup: fp32->bf16 casts, weight reorders, embedding gather, combined bias.
// Gate rows unit-major: new row r <-> orig row o=((r&3)<<9)+(r>>2).
// ---------------------------------------------------------------------------
__global__ __launch_bounds__(256) void setup_cast(
  const float* __restrict__ feats, const int* __restrict__ captions,
  const float* __restrict__ embW, const float* __restrict__ Wf_w,
  const float* __restrict__ Wh_w, const float* __restrict__ W_ih,
  const float* __restrict__ W_hh, const float* __restrict__ b_ih,
  const float* __restrict__ b_hh, const float* __restrict__ out_w,
  u16* __restrict__ feats_bf, u16* __restrict__ outw_bf, u16* __restrict__ Wc,
  u16* __restrict__ WihE, u16* __restrict__ embx, u16* __restrict__ Whw_bf,
  u16* __restrict__ Wf_bf, float* __restrict__ bias_comb)
{
  const long long o0=12845056LL,o1=28246016LL,o2=30343168LL,o3=31391744LL,
                  o4=32702464LL,o5=32964608LL,o6=33226752LL,total=33228800LL;
  for (long long i8=((long long)blockIdx.x*256+threadIdx.x)*8; i8<total;
       i8+=(long long)gridDim.x*256*8){
    const long long i=i8;
    if (i<o0){ pack8(feats_bf+i, feats+i); }
    else if (i<o1){ const long long j=i-o0; const int r=(int)(j>>9);
      if (r<30000) pack8(outw_bf+j, out_w+j); else zero8(outw_bf+j); }
    else if (i<o2){ const long long j=i-o1; const int r=(int)(j>>10), k=(int)(j&1023);
      const int o=((r&3)<<9)+(r>>2);
      const float* s=(k<512)? (W_ih+(size_t)o*1024+512+k) : (W_hh+(size_t)o*512+(k-512));
      pack8(Wc+j, s); }
    else if (i<o3){ const long long j=i-o2; const int r=(int)(j>>9), k=(int)(j&511);
      const int o=((r&3)<<9)+(r>>2);
      pack8(WihE+j, W_ih+(size_t)o*1024+k); }
    else if (i<o4){ const long long j=i-o3; const int m=(int)(j>>9), e=(int)(j&511);
      const int b=m/20, tt=m-b*20; const int idx=captions[b*21+tt];
      if (idx) pack8(embx+j, embW+(size_t)idx*512+e); else zero8(embx+j); }
    else if (i<o5){ const long long j=i-o4; pack8(Whw_bf+j, Wh_w+j); }
    else if (i<o6){ const long long j=i-o5; pack8(Wf_bf+j, Wf_w+j); }
    else { const long long j=i-o6;
      for(int e=0;e<8;++e){ const int r=(int)(j+e); const int o=((r&3)<<9)+(r>>2);
        bias_comb[r]=b_ih[o]+b_hh[o]; } }
  }
}

// ---------------------------------------------------------------------------
// prep: gfeat = mean(feats), h0/c0. h0 (bf16) -> xs h-slot, c0 (fp32) -> cbuf.
// ---------------------------------------------------------------------------
__global__ __launch_bounds__(256) void prep(
  const float* __restrict__ feats, const float* __restrict__ init_w,
  const float* __restrict__ init_b, const float* __restrict__ initc_w,
  const float* __restrict__ initc_b, u16* __restrict__ xs0, float* __restrict__ cbuf)
{
  const int b=blockIdx.x, tid=threadIdx.x, lane=tid&63, w=tid>>6;
  __shared__ float gf[512];
  const float* fb=feats+(size_t)b*196*512;
  float a0=0.f,a1=0.f;
  for(int n=0;n<196;++n){ a0+=fb[(size_t)n*512+tid]; a1+=fb[(size_t)n*512+tid+256]; }
  gf[tid]=a0*(1.f/196.f); gf[tid+256]=a1*(1.f/196.f);
  __syncthreads();
  const int kb=lane*8;
  float g8[8];
#pragma unroll
  for(int e=0;e<8;++e) g8[e]=gf[kb+e];
  for(int j=w*128;j<w*128+128;++j){
    const float* r1=init_w+(size_t)j*512+kb;
    const float* r2=initc_w+(size_t)j*512+kb;
    float s1=0.f,s2=0.f;
#pragma unroll
    for(int e=0;e<8;++e){ s1+=g8[e]*r1[e]; s2+=g8[e]*r2[e]; }
    s1=wsum(s1); s2=wsum(s2);
    if(lane==(j&63)){ xs0[b*1024+512+j]=f2bf(s1+init_b[j]); cbuf[b*512+j]=s2+initc_b[j]; }
  }
}

// ---------------------------------------------------------------------------
// attn_step: 128 blocks x 1024 threads (16 waves). r16 structure + PREFETCH-
// BEFORE-BARRIER: each phase's first-iteration loads are issued before the
// preceding __syncthreads so their latency hides under the prior phase's
// compute. Values/FP order bit-identical to r16.
// Prologue (t>0): LSTM for step t-1 (8 gpart K-slices).
// ---------------------------------------------------------------------------
__global__ __launch_bounds__(1024) void attn_step(
  const u16* __restrict__ fproj, const u16* __restrict__ feats_bf,
  u16* __restrict__ xs, const u16* __restrict__ Whw,
  const float* __restrict__ Whb, const float* __restrict__ vw,
  const float* __restrict__ gemb,
  const float* __restrict__ gpart, float* __restrict__ cbuf,
  u16* __restrict__ h_all, int t)
{
  const int b=blockIdx.x, tid=threadIdx.x, lane=tid&63, w=tid>>6;
  __shared__ float part[16][512];
  __shared__ float hsf[512], hp[512], sc[208], red[16];
  const int kb=lane*8;
  const int j0=w*32;
  float h8[8];

  // PREFETCH: hproj iteration-0 rows (independent of the LSTM prologue)
  short8 wv0[8];
#pragma unroll
  for(int r=0;r<8;++r) wv0[r]=*(const short8*)(Whw+(size_t)(j0+r)*512+kb);

  if (t>0){
    if (tid<512){
      const int u=tid;
      float4 g4=*(const float4*)&gemb[((size_t)b*20+(t-1))*2048+u*4];
#pragma unroll
      for(int kz=0;kz<8;++kz){
        const float4 p=*(const float4*)&gpart[((size_t)kz*128+b)*2048+u*4];
        g4.x+=p.x; g4.y+=p.y; g4.z+=p.z; g4.w+=p.w;
      }
      const float cn=sigm(g4.y)*cbuf[b*512+u]+sigm(g4.x)*tanhx(g4.z);
      const float hn=sigm(g4.w)*tanhx(cn);
      cbuf[b*512+u]=cn;
      const u16 hb=f2bf(hn);
      xs[b*1024+512+u]=hb;
      h_all[((size_t)b*20+(t-1))*512+u]=hb;
      hsf[u]=bf2f(hb);
    }
  } else {
    if (tid<512) hsf[tid]=bf2f(xs[b*1024+512+tid]);
  }
  __syncthreads();
#pragma unroll
  for(int e=0;e<8;++e) h8[e]=hsf[kb+e];

  // hproj: wave w owns rows [32w, 32w+32), 8 rows per block; iter 0 prefetched
  auto hblock=[&](const short8* wv, int j){
    float s[8];
#pragma unroll
    for(int r=0;r<8;++r) s[r]=0.f;
#pragma unroll
    for(int e=0;e<8;++e){
      const float he=h8[e];
#pragma unroll
      for(int r=0;r<8;++r) s[r]+=he*bf2f((u16)wv[r][e]);
    }
#pragma unroll
    for(int r=0;r<8;++r) s[r]=wsum(s[r]);
    if(lane==0){
#pragma unroll
      for(int r=0;r<8;++r) hp[j+r]=s[r]+Whb[j+r];
    }
  };
  hblock(wv0, j0);
#pragma unroll
  for(int jj=8;jj<32;jj+=8){
    const int j=j0+jj;
    short8 wv[8];
#pragma unroll
    for(int r=0;r<8;++r) wv[r]=*(const short8*)(Whw+(size_t)(j+r)*512+kb);
    hblock(wv, j);
  }

  // PREFETCH: scores iteration-0 fproj rows (independent of hp)
  short8 fp0[6];
#pragma unroll
  for(int r=0;r<6;++r) fp0[r]=*(const short8*)(fproj+((size_t)b*196+w+16*r)*512+kb);
  __syncthreads();

  // scores: v·tanh(f+p) = v - 2v/(exp(2(f+p))+1); 6-row batching, raw scores
  float p2[8], vm2[8];
  float sv=0.f;
#pragma unroll
  for(int e=0;e<8;++e){
    const float p=hp[kb+e], v=vw[kb+e];
    p2[e]=2.f*p; vm2[e]=-2.f*v; sv+=v;
  }
  auto sblock=[&](const short8* f, int n0){
    float s[6];
#pragma unroll
    for(int r=0;r<6;++r) s[r]=sv;
#pragma unroll
    for(int e=0;e<8;++e){
#pragma unroll
      for(int r=0;r<6;++r)
        s[r]+=__fdividef(vm2[e],__expf(fmaf(bf2f((u16)f[r][e]),2.f,p2[e]))+1.f);
    }
#pragma unroll
    for(int r=0;r<6;++r) s[r]=wsum(s[r]);
    if(lane==0){
#pragma unroll
      for(int r=0;r<6;++r) sc[n0+16*r]=s[r];
    }
  };
  sblock(fp0, w);
  {
    const int n0=w+96;
    short8 f[6];
#pragma unroll
    for(int r=0;r<6;++r) f[r]=*(const short8*)(fproj+((size_t)b*196+n0+16*r)*512+kb);
    sblock(f, n0);
  }
  {
    const int n=w+192;
    if (n<196){
      short8 f0=*(const short8*)(fproj+((size_t)b*196+n)*512+kb);
      float s0=sv;
#pragma unroll
      for(int e=0;e<8;++e)
        s0+=__fdividef(vm2[e],__expf(fmaf(bf2f((u16)f0[e]),2.f,p2[e]))+1.f);
      s0=wsum(s0);
      if(lane==0) sc[n]=s0;
    }
  }

  // PREFETCH: ctx iteration-0 feats rows (independent of sc)
  short8 vf0[6];
#pragma unroll
  for(int r=0;r<6;++r) vf0[r]=*(const short8*)(feats_bf+((size_t)b*196+w+16*r)*512+kb);
  __syncthreads();

  // softmax (no-max variant): pv=exp(s); tot=sum; raw weights in sc,
  // normalization deferred to ctx part-write.
  float pv=(tid<196)? __expf(sc[tid]) : 0.f;
  float ps=wsum(pv);
  if(lane==0) red[w]=ps;
  if(tid<196) sc[tid]=pv;
  __syncthreads();
  float tot=red[0];
#pragma unroll
  for(int i=1;i<16;++i) tot+=red[i];
  const float inv=__fdividef(1.f,tot);

  // ctx partials: wave w accumulates rows w+16i, 6-row batching; iter 0 prefetched
  float a8[8];
#pragma unroll
  for(int e=0;e<8;++e) a8[e]=0.f;
  auto cblock=[&](const short8* v, int n0){
    float wn[6];
#pragma unroll
    for(int r=0;r<6;++r) wn[r]=sc[n0+16*r];
#pragma unroll
    for(int e=0;e<8;++e){
      float acc=a8[e];
#pragma unroll
      for(int r=0;r<6;++r) acc+=wn[r]*bf2f((u16)v[r][e]);
      a8[e]=acc;
    }
  };
  cblock(vf0, w);
  {
    const int n0=w+96;
    short8 v[6];
#pragma unroll
    for(int r=0;r<6;++r) v[r]=*(const short8*)(feats_bf+((size_t)b*196+n0+16*r)*512+kb);
    cblock(v, n0);
  }
  {
    const int n=w+192;
    if (n<196){
      short8 v0=*(const short8*)(feats_bf+((size_t)b*196+n)*512+kb);
      const float wn=sc[n];
#pragma unroll
      for(int e=0;e<8;++e) a8[e]+=wn*bf2f((u16)v0[e]);
    }
  }
#pragma unroll
  for(int e=0;e<8;++e) a8[e]*=inv;
  *(float4*)&part[w][kb]  =*(float4*)&a8[0];
  *(float4*)&part[w][kb+4]=*(float4*)&a8[4];
  __syncthreads();
  if (tid<512){
    float s=0.f;
#pragma unroll
    for(int i=0;i<16;++i) s+=part[i][tid];
    xs[b*1024+tid]=f2bf(s);
  }
}

// ---------------------------------------------------------------------------
// lstm_fin: LSTM for the final step (t=19) — h_all only. 8 gpart slices.
// ---------------------------------------------------------------------------
__global__ __launch_bounds__(512) void lstm_fin(
  const float* __restrict__ gemb, const float* __restrict__ gpart,
  const float* __restrict__ cbuf, u16* __restrict__ h_all)
{
  const int b=blockIdx.x, u=threadIdx.x;
  float4 g4=*(const float4*)&gemb[((size_t)b*20+19)*2048+u*4];
#pragma unroll
  for(int kz=0;kz<8;++kz){
    const float4 p=*(const float4*)&gpart[((size_t)kz*128+b)*2048+u*4];
    g4.x+=p.x; g4.y+=p.y; g4.z+=p.z; g4.w+=p.w;
  }
  const float cn=sigm(g4.y)*cbuf[b*512+u]+sigm(g4.x)*tanhx(g4.z);
  const float hn=sigm(g4.w)*tanhx(cn);
  h_all[((size_t)b*20+19)*512+u]=f2bf(hn);
}

// ---------------------------------------------------------------------------
// gemm_bt: C[M,N] = A[M,K] * B[N,K]^T, 128x128 tile, m97 structure.
// MODE 0: bf16 out + bias   MODE 1: f32 out + bias
// MODE 2: f32 + col guard, transposed grid (out_w L2 reuse)
// MODE 4: K-split partial (blockIdx.y = kz, base += kz*K, bm=0), 8 x K=128
// ---------------------------------------------------------------------------
template<int MODE>
__global__ __launch_bounds__(256) void gemm_bt(
  const u16* __restrict__ A, int lda, const u16* __restrict__ Bw, int ldb, int K,
  const float* __restrict__ bias, float* __restrict__ outf, u16* __restrict__ outb,
  int ncols)
{
  const int bm=(MODE==4)? 0 : ((MODE==2)? blockIdx.x*128 : blockIdx.y*128);
  const int bn=(MODE==2)? blockIdx.y*128 : blockIdx.x*128;
  const int kz=(MODE==4)? blockIdx.y : 0;
  const u16* __restrict__ Ap=A +(size_t)kz*K;
  const u16* __restrict__ Bp=Bw+(size_t)kz*K;
  const int tid=threadIdx.x, lane=tid&63, wave=tid>>6;
  const int wr=(wave>>1)*64, wc=(wave&1)*64;
  __shared__ u16 As[128*32], Bs[128*32];
  f32x4 acc[4][4]={};
  const int srow=tid>>2, scol=(tid&3)*8;
  for(int k0=0;k0<K;k0+=32){
    gll16(Ap+(size_t)(bm+srow)*lda    +k0+scol, As+tid*8);
    gll16(Ap+(size_t)(bm+64+srow)*lda +k0+scol, As+2048+tid*8);
    gll16(Bp+(size_t)(bn+srow)*ldb    +k0+scol, Bs+tid*8);
    gll16(Bp+(size_t)(bn+64+srow)*ldb +k0+scol, Bs+2048+tid*8);
    __syncthreads();
    short8 af[4], bfr[4];
    const int ro=lane&15, ko=(lane>>4)*8;
#pragma unroll
    for(int m=0;m<4;++m) af[m]=*(const short8*)(As+(wr+m*16+ro)*32+ko);
#pragma unroll
    for(int n=0;n<4;++n) bfr[n]=*(const short8*)(Bs+(wc+n*16+ro)*32+ko);
#pragma unroll
    for(int m=0;m<4;++m)
#pragma unroll
      for(int n=0;n<4;++n) acc[m][n]=mfma16(af[m],bfr[n],acc[m][n]);
    __syncthreads();
  }
  asm volatile("s_nop 7\ns_nop 7\ns_nop 7");  // MFMA->VALU hazard guard
  const int ro4=(lane>>4)*4, co=lane&15;
#pragma unroll
  for(int m=0;m<4;++m)
#pragma unroll
    for(int n=0;n<4;++n)
#pragma unroll
      for(int j=0;j<4;++j){
        const int r=bm+wr+m*16+ro4+j, c=bn+wc+n*16+co;
        if constexpr (MODE==0)      outb[(size_t)r*ncols+c]=f2bf(acc[m][n][j]+bias[c]);
        else if constexpr (MODE==1) outf[(size_t)r*ncols+c]=acc[m][n][j]+bias[c];
        else if constexpr (MODE==2){ if (c<ncols) outf[(size_t)r*ncols+c]=acc[m][n][j]+bias[c]; }
        else                        outf[((size_t)kz*128+r)*ncols+c]=acc[m][n][j];
      }
}

// ---------------------------------------------------------------------------
extern "C" void kernel_launch(void* const* d_in, const int* in_sizes, int n_in,
                              void* d_out, int out_size, void* d_ws, size_t ws_size,
                              hipStream_t stream) {
  const float* feats   =(const float*)d_in[0];
  const int*   captions=(const int*)  d_in[1];
  const float* embW    =(const float*)d_in[2];
  const float* Wf_w    =(const float*)d_in[3];
  const float* Wf_b    =(const float*)d_in[4];
  const float* Wh_w    =(const float*)d_in[5];
  const float* Wh_b    =(const float*)d_in[6];
  const float* v_w     =(const float*)d_in[7];
  const float* v_b     =(const float*)d_in[8];
  const float* W_ih    =(const float*)d_in[9];
  const float* W_hh    =(const float*)d_in[10];
  const float* b_ih    =(const float*)d_in[11];
  const float* b_hh    =(const float*)d_in[12];
  const float* init_w  =(const float*)d_in[13];
  const float* init_b  =(const float*)d_in[14];
  const float* initc_w =(const float*)d_in[15];
  const float* initc_b =(const float*)d_in[16];
  const float* out_w   =(const float*)d_in[17];
  const float* out_b   =(const float*)d_in[18];
  float* out=(float*)d_out;
  char* ws=(char*)d_ws;
  (void)v_b;

  u16*   feats_bf =(u16*)  (ws+0);
  u16*   fproj    =(u16*)  (ws+25690112);
  u16*   outw_bf  =(u16*)  (ws+51380224);
  u16*   Wc       =(u16*)  (ws+82182144);
  u16*   WihE     =(u16*)  (ws+86376448);
  u16*   Whw_bf   =(u16*)  (ws+88473600);
  u16*   Wf_bf    =(u16*)  (ws+88997888);
  u16*   embx     =(u16*)  (ws+89522176);
  u16*   h_all    =(u16*)  (ws+92143616);
  u16*   xs0      =(u16*)  (ws+94765056);
  float* gemb     =(float*)(ws+95289344);
  float* cbuf     =(float*)(ws+116260864);
  float* bias_comb=(float*)(ws+116785152);
  float* gpart    =(float*)(ws+116793344);  // 8 x 128 x 2048 f32 = 8 MB

  setup_cast<<<4096,256,0,stream>>>(feats,captions,embW,Wf_w,Wh_w,W_ih,W_hh,b_ih,b_hh,out_w,
                                    feats_bf,outw_bf,Wc,WihE,embx,Whw_bf,Wf_bf,bias_comb);
  prep<<<128,256,0,stream>>>(feats,init_w,init_b,initc_w,initc_b,xs0,cbuf);
  // fproj = feats_bf @ Wf^T + Wf_b  (25088 x 512, K=512) -> bf16
  gemm_bt<0><<<dim3(4,196),256,0,stream>>>(feats_bf,512,Wf_bf,512,512,
      Wf_b,nullptr,fproj,512);
  // gemb = embx @ WihE^T + (b_ih+b_hh)  (2560 x 2048, K=512) -> f32
  gemm_bt<1><<<dim3(16,20),256,0,stream>>>(embx,512,WihE,512,512,
      bias_comb,gemb,nullptr,2048);

  for(int t=0;t<20;++t){
    attn_step<<<128,1024,0,stream>>>(fproj,feats_bf,xs0,Whw_bf,Wh_b,v_w,
                                     gemb,gpart,cbuf,h_all,t);
    // gates partials: xs(128x1024) @ Wc^T(2048x1024), K-split 8x128 -> gpart
    gemm_bt<4><<<dim3(16,8),256,0,stream>>>(xs0,1024,Wc,1024,128,
        nullptr,gpart,nullptr,2048);
  }
  lstm_fin<<<128,512,0,stream>>>(gemb,gpart,cbuf,h_all);
  // logits = h_all @ out_w^T + out_b, transposed grid for out_w L2 reuse
  gemm_bt<2><<<dim3(20,235),256,0,stream>>>(h_all,512,outw_bf,512,512,
      out_b,out,nullptr,30000);
}